// Round 17
// baseline (172.219 us; speedup 1.0000x reference)
//
#include <hip/hip_runtime.h>

#define GROUPS 32
#define EPS 1e-5f

typedef unsigned short u16;
typedef __bf16 bf16x8 __attribute__((ext_vector_type(8)));
typedef float f32x4 __attribute__((ext_vector_type(4)));

__device__ __forceinline__ u16 f2bf(float f) {
  unsigned x = __builtin_bit_cast(unsigned, f);
  x += 0x7FFFu + ((x >> 16) & 1u);
  return (u16)(x >> 16);
}
__device__ __forceinline__ float bf2f(u16 u) {
  unsigned x = ((unsigned)u) << 16;
  return __builtin_bit_cast(float, x);
}

__device__ __forceinline__ void gload_lds16(const void* g, void* l) {
  __builtin_amdgcn_global_load_lds(
      (const __attribute__((address_space(1))) void*)g,
      (__attribute__((address_space(3))) void*)l, 16, 0, 0);
}

// ======== prep: groupnorm + weight cvt + bias concat + lsum zero ==========
// blocks [0,512): groupnorm;  [512,1536): weight fp32->bf16 (4 x 256);
// [1536,1542): bias concat bq||bk||bv -> bqkv[3C];  [1542,1558): zero lsum.
__global__ __launch_bounds__(256) void prep_kernel(
    const float* __restrict__ x, const float* __restrict__ gamma,
    const float* __restrict__ beta, u16* __restrict__ HT,
    const float* __restrict__ wq, const float* __restrict__ wk,
    const float* __restrict__ wv, const float* __restrict__ wo,
    const float* __restrict__ bq, const float* __restrict__ bk,
    const float* __restrict__ bv,
    u16* __restrict__ Wqkv, u16* __restrict__ Wo,
    float* __restrict__ bqkv, float* __restrict__ lsum,
    int C, int S, int CC, int NG) {
  __shared__ float xs[16 * 1024];
  __shared__ float rs[4], rss[4];
  int b = blockIdx.x;
  int tid = threadIdx.x;

  if (b >= NG) {  // ---- cvt / bias / zero branch
    int cb = b - NG;
    if (cb < 1024) {          // weight convert: weight w, block blk
      int w = cb >> 8, blk = cb & 255;
      const float* src;
      u16* dst;
      switch (w) {
        case 0: src = wq; dst = Wqkv; break;
        case 1: src = wk; dst = Wqkv + CC; break;
        case 2: src = wv; dst = Wqkv + 2 * CC; break;
        default: src = wo; dst = Wo; break;
      }
      int i = (blk * 256 + tid) * 4;
      float4 v = *(const float4*)&src[i];
      ushort4 o;
      o.x = f2bf(v.x); o.y = f2bf(v.y); o.z = f2bf(v.z); o.w = f2bf(v.w);
      *(ushort4*)&dst[i] = o;
    } else if (cb < 1030) {   // bias concat (3C = 1536 = 6 x 256)
      int j = (cb - 1024) * 256 + tid;
      if (j < C) bqkv[j] = bq[j];
      else if (j < 2 * C) bqkv[j] = bk[j - C];
      else bqkv[j] = bv[j - 2 * C];
    } else {                  // zero lsum (N*S = 16384 floats, 16 blocks)
      int i = (cb - 1030) * 1024 + tid * 4;
      *(float4*)&lsum[i] = make_float4(0.f, 0.f, 0.f, 0.f);
    }
    return;
  }

  // ---- groupnorm branch
  const int cpg = C / GROUPS;  // 16
  int n = b / GROUPS;
  int g = b % GROUPS;
  const float* xb = x + ((size_t)n * C + (size_t)g * cpg) * S;
  int cnt = cpg * S;
  float s = 0.f, ss = 0.f;
  for (int i = tid * 4; i < cnt; i += 256 * 4) {
    float4 v = *(const float4*)&xb[i];
    *(float4*)&xs[i] = v;
    s += v.x + v.y + v.z + v.w;
    ss += v.x * v.x + v.y * v.y + v.z * v.z + v.w * v.w;
  }
  for (int o = 32; o > 0; o >>= 1) {
    s += __shfl_xor(s, o);
    ss += __shfl_xor(ss, o);
  }
  int wave = tid >> 6, lane = tid & 63;
  if (lane == 0) { rs[wave] = s; rss[wave] = ss; }
  __syncthreads();
  float S1 = rs[0] + rs[1] + rs[2] + rs[3];
  float S2 = rss[0] + rss[1] + rss[2] + rss[3];
  float mean = S1 / (float)cnt;
  float var = S2 / (float)cnt - mean * mean;
  float rstd = rsqrtf(var + EPS);
  float gm[16], bt[16];
#pragma unroll
  for (int c = 0; c < 16; ++c) {
    float gmv = gamma[g * cpg + c] * rstd;
    gm[c] = gmv;
    bt[c] = beta[g * cpg + c] - mean * gmv;
  }
  for (int i = 0; i < S; i += 256) {
    int sp = i + tid;
    u16 outv[16];
#pragma unroll
    for (int c = 0; c < 16; ++c) {
      float h = xs[c * 1024 + sp] * gm[c] + bt[c];
      outv[c] = f2bf(h);
    }
    u16* dst = HT + ((size_t)n * S + sp) * C + g * cpg;
    *(int4*)dst = *(int4*)&outv[0];
    *(int4*)&dst[8] = *(int4*)&outv[8];
  }
}

// =================== 256x128x32 2-phase GEMM body (8 waves) ================
// Round-8/15 best-measured structure. Batch->XCD z-map. 0-conflict LDS line
// layout: two rows interleave into one 64-elem line; granule (l,p) holds
// global (row=2l+(q>>2), kslot=q&3), q=p^(l&7).
// epi_mode: 0 = normal (scale/bias/residual/store)
//           1 = expP: write f2bf(exp(acc*scale)); atomic row-sum into epi_ptr
//           2 = colscale: v = acc*scale*(1/epi_ptr[col]) + bias + residual
__device__ __forceinline__ void gemm_body(
    int bid, int nblk,
    const u16* __restrict__ A, long lda, long strideA,
    const u16* __restrict__ B, long ldb, long strideB,
    void* __restrict__ Out, long ldo, long strideO, int out_fp32,
    const float* __restrict__ bias, int bias_mode,  // 0 none, 1 row, 2 col
    float scale, const float* __restrict__ residual, int K,
    int nbx, int nby, u16* lds, int epi_mode, float* epi_ptr) {
  u16* As0 = lds;
  u16* Bs0 = lds + 8192;
  u16* As1 = lds + 12288;
  u16* Bs1 = lds + 20480;

  int tid = threadIdx.x;
  int wave = tid >> 6, lane = tid & 63;
  int wr = wave >> 1, wc = wave & 1;   // 4 x 2 wave grid, 64x64 per wave
  int l15 = lane & 15, l4 = lane >> 4;

  int tilesPB = nbx * nby;
  int nz = nblk / tilesPB;
  int z, rem;
  if ((nz & 7) == 0) {        // batch->XCD mapping
    int e = bid & 7, j = bid >> 3;
    z = e + 8 * (j / tilesPB);
    rem = j % tilesPB;
  } else {
    int swz = ((nblk & 7) == 0) ? (bid & 7) * (nblk >> 3) + (bid >> 3) : bid;
    z = swz / tilesPB; rem = swz % tilesPB;
  }
  int bx = rem % nbx, by = rem / nbx;

  const u16* Ab = A + (long)z * strideA + (long)by * 256 * lda;
  const u16* Bb = B + (long)z * strideB + (long)bx * 128 * ldb;

  auto STAGE = [&](u16* Ad, u16* Bd, int kt) {
#pragma unroll
    for (int i = 0; i < 2; ++i) {       // A granules
      int c = i * 512 + tid;
      int l = c >> 3, p = c & 7;
      int q = p ^ (l & 7);
      int row = 2 * l + (q >> 2);
      long koff = (long)kt * 32 + (q & 3) * 8;
      int lbase = (i * 512 + wave * 64) * 8;
      gload_lds16(Ab + (long)row * lda + koff, Ad + lbase);
    }
    {                                   // B granules
      int c = tid;
      int l = c >> 3, p = c & 7;
      int q = p ^ (l & 7);
      int row = 2 * l + (q >> 2);
      long koff = (long)kt * 32 + (q & 3) * 8;
      int lbase = (wave * 64) * 8;
      gload_lds16(Bb + (long)row * ldb + koff, Bd + lbase);
    }
  };

  f32x4 acc[4][4] = {};

  auto COMPUTE = [&](const u16* Asrc, const u16* Bsrc) {
    bf16x8 af[4], bfr[4];
#pragma unroll
    for (int m = 0; m < 4; ++m) {
      int R = wr * 64 + m * 16 + l15;
      int line = R >> 1;
      int p = ((R & 1) * 4 + l4) ^ (line & 7);
      af[m] = *(const bf16x8*)&Asrc[line * 64 + p * 8];
    }
#pragma unroll
    for (int n = 0; n < 4; ++n) {
      int R = wc * 64 + n * 16 + l15;
      int line = R >> 1;
      int p = ((R & 1) * 4 + l4) ^ (line & 7);
      bfr[n] = *(const bf16x8*)&Bsrc[line * 64 + p * 8];
    }
#pragma unroll
    for (int m = 0; m < 4; ++m)
#pragma unroll
      for (int n = 0; n < 4; ++n)
        acc[m][n] = __builtin_amdgcn_mfma_f32_16x16x32_bf16(
            af[m], bfr[n], acc[m][n], 0, 0, 0);
  };

  int NT = K >> 5;
  u16 *Ar = As0, *Br = Bs0, *Aw = As1, *Bw = Bs1;

  STAGE(Ar, Br, 0);
  asm volatile("s_waitcnt vmcnt(0)" ::: "memory");
  __builtin_amdgcn_sched_barrier(0);
  __builtin_amdgcn_s_barrier();
  __builtin_amdgcn_sched_barrier(0);

  for (int t = 0; t < NT - 1; ++t) {
    STAGE(Aw, Bw, t + 1);       // issue next-tile loads first
    COMPUTE(Ar, Br);            // they fly under ds_read + MFMA
    asm volatile("s_waitcnt vmcnt(0)" ::: "memory");
    __builtin_amdgcn_sched_barrier(0);
    __builtin_amdgcn_s_barrier();
    __builtin_amdgcn_sched_barrier(0);
    u16* tp;
    tp = Ar; Ar = Aw; Aw = tp;
    tp = Br; Br = Bw; Bw = tp;
  }
  COMPUTE(Ar, Br);

  long orow0 = (long)by * 256 + wr * 64;
  long ocol0 = (long)bx * 128 + wc * 64;
  long rows_pb = 256L * nby;
  long cols_pb = 128L * nbx;

  float inv4[4];
  if (epi_mode == 2) {
#pragma unroll
    for (int n = 0; n < 4; ++n)
      inv4[n] = 1.f / epi_ptr[z * cols_pb + ocol0 + n * 16 + l15];
  }
  float rowpart[4][4];
  if (epi_mode == 1) {
#pragma unroll
    for (int m = 0; m < 4; ++m)
#pragma unroll
      for (int r = 0; r < 4; ++r) rowpart[m][r] = 0.f;
  }

#pragma unroll
  for (int m = 0; m < 4; ++m) {
#pragma unroll
    for (int n = 0; n < 4; ++n) {
#pragma unroll
      for (int r = 0; r < 4; ++r) {
        long row = orow0 + m * 16 + l4 * 4 + r;
        long col = ocol0 + n * 16 + l15;
        long off = (long)z * strideO + row * ldo + col;
        float v = acc[m][n][r] * scale;
        if (epi_mode == 1) {
          u16 e = f2bf(__expf(v));
          ((u16*)Out)[off] = e;
          rowpart[m][r] += bf2f(e);
        } else {
          if (epi_mode == 2) v *= inv4[n];
          if (bias_mode == 1) v += bias[row];
          else if (bias_mode == 2) v += bias[col];
          if (residual) v += residual[off];
          if (out_fp32) ((float*)Out)[off] = v;
          else ((u16*)Out)[off] = f2bf(v);
        }
      }
    }
  }

  if (epi_mode == 1) {  // reduce across the 16 cols each lane-group covers
#pragma unroll
    for (int m = 0; m < 4; ++m)
#pragma unroll
      for (int r = 0; r < 4; ++r) {
        float t = rowpart[m][r];
        t += __shfl_xor(t, 1);
        t += __shfl_xor(t, 2);
        t += __shfl_xor(t, 4);
        t += __shfl_xor(t, 8);
        if (l15 == 0) {
          long row = orow0 + m * 16 + l4 * 4 + r;
          atomicAdd(&epi_ptr[z * rows_pb + row], t);
        }
      }
  }
}

__global__ __launch_bounds__(512, 4) void gemm256x128_kernel(
    const u16* __restrict__ A, long lda, long strideA,
    const u16* __restrict__ B, long ldb, long strideB,
    void* __restrict__ Out, long ldo, long strideO, int out_fp32,
    const float* __restrict__ bias, int bias_mode,
    float scale, const float* __restrict__ residual, int K, int nbx, int nby,
    int epi_mode, float* epi_ptr) {
  __shared__ u16 lds[24576];
  gemm_body(blockIdx.x, gridDim.x, A, lda, strideA, B, ldb, strideB,
            Out, ldo, strideO, out_fp32, bias, bias_mode, scale, residual,
            K, nbx, nby, lds, epi_mode, epi_ptr);
}

// -------- merged expP-GEMM + VO-GEMM: one dispatch ------------------------
// blocks [0,nP): expP[s][t] = exp(scl*sum_c Q[s][c]K[t][c]); atomic lsum
// blocks [nP,grid): VO[c][t] = sum_k Wo[c][k]*VT[t][k]   (VT = QKVT cols 2C+)
__global__ __launch_bounds__(512, 4) void pvo_kernel(
    const u16* __restrict__ QKVT, const u16* __restrict__ Wo,
    u16* __restrict__ P, u16* __restrict__ VO, float* __restrict__ lsum,
    float scl, int nP, int C, int S) {
  __shared__ u16 lds[24576];
  long S3C = (long)S * 3 * C, SC = (long)S * C, SS = (long)S * S;
  if ((int)blockIdx.x < nP) {
    gemm_body(blockIdx.x, nP, QKVT, 3 * C, S3C, QKVT + C, 3 * C, S3C,
              P, S, SS, 0, nullptr, 0, scl, nullptr, C,
              S / 128, S / 256, lds, 1, lsum);
  } else {
    gemm_body(blockIdx.x - nP, gridDim.x - nP, Wo, C, 0,
              QKVT + 2 * C, 3 * C, S3C, VO, S, SC, 0, nullptr, 0, 1.f,
              nullptr, C, S / 128, C / 256, lds, 0, nullptr);
  }
}

extern "C" void kernel_launch(void* const* d_in, const int* in_sizes, int n_in,
                              void* d_out, int out_size, void* d_ws, size_t ws_size,
                              hipStream_t stream) {
  const float* x = (const float*)d_in[0];
  const float* gamma = (const float*)d_in[1];
  const float* beta = (const float*)d_in[2];
  const float* wq = (const float*)d_in[3];
  const float* bq = (const float*)d_in[4];
  const float* wk = (const float*)d_in[5];
  const float* bk = (const float*)d_in[6];
  const float* wv = (const float*)d_in[7];
  const float* bv = (const float*)d_in[8];
  const float* wo = (const float*)d_in[9];
  const float* bo = (const float*)d_in[10];

  const int C = 512, S = 1024;
  const int N = in_sizes[0] / (C * S);  // 16
  const long SC = (long)S * C;
  const long S3C = (long)S * 3 * C;
  const long SS = (long)S * S;
  const int CC = C * C;

  char* ws = (char*)d_ws;
  const size_t MB = 1024 * 1024;
  u16* HT = (u16*)(ws + 0 * MB);      // [N,S,C]  0..16 MB (dead after proj)
  u16* VO = HT;                       // [N,C,S]  overlays HT
  u16* QKVT = (u16*)(ws + 16 * MB);   // [N,S,3C] 16..64 MB
  u16* P = (u16*)(ws + 64 * MB);      // [N,S,S]  64..96 MB
  u16* Wqkv = (u16*)(ws + 96 * MB);   // [3C,C]   1.5 MB
  u16* Wo = Wqkv + 3 * CC;            // [C,C]    0.5 MB
  float* bqkv = (float*)(Wo + CC);    // [3C]
  float* lsum = bqkv + 3 * C;         // [N*S] fp32 row sums of expP

  const int NG = N * GROUPS;          // 512

  // prep: groupnorm + weight cvt + bias concat + zero lsum, one dispatch
  prep_kernel<<<dim3(NG + 1024 + 6 + 16), 256, 0, stream>>>(
      x, gamma, beta, HT, wq, wk, wv, wo, bq, bk, bv, Wqkv, Wo, bqkv, lsum,
      C, S, CC, NG);

  const float scl = 1.0f / sqrtf((float)C);
  const int nP = (S / 256) * (S / 128) * N;        // 512
  const int nVO = (C / 256) * (S / 128) * N;       // 256

  // uniform QKV projection: QKVT[s][j] = sum_c HT[s][c]*Wqkv[j][c] + bqkv[j]
  gemm256x128_kernel<<<dim3((S / 256) * (3 * C / 128) * N), 512, 0, stream>>>(
      HT, C, SC, Wqkv, C, 0, QKVT, 3 * C, S3C, 0, bqkv, 2, 1.f, nullptr, C,
      3 * C / 128, S / 256, 0, nullptr);
  // merged: expP (+ lsum)  ||  VO = Wo*V
  pvo_kernel<<<dim3(nP + nVO), 512, 0, stream>>>(
      QKVT, Wo, P, VO, lsum, scl, nP, C, S);
  // out[c][s] = x + bo[c] + (sum_t expP[s][t]*VO[c][t]) / lsum[s]   (fp32)
  gemm256x128_kernel<<<dim3((C / 256) * (S / 128) * N), 512, 0, stream>>>(
      VO, S, SC, P, S, SS, d_out, S, SC, 1, bo, 1, 1.f, x, S,
      S / 128, C / 256, 2, lsum);
}

// Round 18
// 168.756 us; speedup vs baseline: 1.0205x; 1.0205x over previous
//
#include <hip/hip_runtime.h>

#define GROUPS 32
#define EPS 1e-5f

typedef unsigned short u16;
typedef __bf16 bf16x8 __attribute__((ext_vector_type(8)));
typedef float f32x4 __attribute__((ext_vector_type(4)));

__device__ __forceinline__ u16 f2bf(float f) {
  unsigned x = __builtin_bit_cast(unsigned, f);
  x += 0x7FFFu + ((x >> 16) & 1u);
  return (u16)(x >> 16);
}
__device__ __forceinline__ float bf2f(u16 u) {
  unsigned x = ((unsigned)u) << 16;
  return __builtin_bit_cast(float, x);
}

__device__ __forceinline__ void gload_lds16(const void* g, void* l) {
  __builtin_amdgcn_global_load_lds(
      (const __attribute__((address_space(1))) void*)g,
      (__attribute__((address_space(3))) void*)l, 16, 0, 0);
}

// ======== prep: groupnorm + weight cvt + bias concat + lsum zero ==========
__global__ __launch_bounds__(256) void prep_kernel(
    const float* __restrict__ x, const float* __restrict__ gamma,
    const float* __restrict__ beta, u16* __restrict__ HT,
    const float* __restrict__ wq, const float* __restrict__ wk,
    const float* __restrict__ wv, const float* __restrict__ wo,
    const float* __restrict__ bq, const float* __restrict__ bk,
    u16* __restrict__ Wqk, u16* __restrict__ Wv, u16* __restrict__ Wo,
    float* __restrict__ bqk, float* __restrict__ lsum,
    int C, int S, int CC, int NG) {
  __shared__ float xs[16 * 1024];
  __shared__ float rs[4], rss[4];
  int b = blockIdx.x;
  int tid = threadIdx.x;

  if (b >= NG) {  // ---- cvt / bias / zero branch
    int cb = b - NG;
    if (cb < 1024) {          // weight convert
      int w = cb >> 8, blk = cb & 255;
      const float* src;
      u16* dst;
      switch (w) {
        case 0: src = wq; dst = Wqk; break;
        case 1: src = wk; dst = Wqk + CC; break;
        case 2: src = wv; dst = Wv; break;
        default: src = wo; dst = Wo; break;
      }
      int i = (blk * 256 + tid) * 4;
      float4 v = *(const float4*)&src[i];
      ushort4 o;
      o.x = f2bf(v.x); o.y = f2bf(v.y); o.z = f2bf(v.z); o.w = f2bf(v.w);
      *(ushort4*)&dst[i] = o;
    } else if (cb < 1028) {   // bias concat
      int j = (cb - 1024) * 256 + tid;
      if (j < C) bqk[j] = bq[j];
      else if (j < 2 * C) bqk[j] = bk[j - C];
    } else {                  // zero lsum
      int i = (cb - 1028) * 1024 + tid * 4;
      *(float4*)&lsum[i] = make_float4(0.f, 0.f, 0.f, 0.f);
    }
    return;
  }

  // ---- groupnorm branch
  const int cpg = C / GROUPS;  // 16
  int n = b / GROUPS;
  int g = b % GROUPS;
  const float* xb = x + ((size_t)n * C + (size_t)g * cpg) * S;
  int cnt = cpg * S;
  float s = 0.f, ss = 0.f;
  for (int i = tid * 4; i < cnt; i += 256 * 4) {
    float4 v = *(const float4*)&xb[i];
    *(float4*)&xs[i] = v;
    s += v.x + v.y + v.z + v.w;
    ss += v.x * v.x + v.y * v.y + v.z * v.z + v.w * v.w;
  }
  for (int o = 32; o > 0; o >>= 1) {
    s += __shfl_xor(s, o);
    ss += __shfl_xor(ss, o);
  }
  int wave = tid >> 6, lane = tid & 63;
  if (lane == 0) { rs[wave] = s; rss[wave] = ss; }
  __syncthreads();
  float S1 = rs[0] + rs[1] + rs[2] + rs[3];
  float S2 = rss[0] + rss[1] + rss[2] + rss[3];
  float mean = S1 / (float)cnt;
  float var = S2 / (float)cnt - mean * mean;
  float rstd = rsqrtf(var + EPS);
  float gm[16], bt[16];
#pragma unroll
  for (int c = 0; c < 16; ++c) {
    float gmv = gamma[g * cpg + c] * rstd;
    gm[c] = gmv;
    bt[c] = beta[g * cpg + c] - mean * gmv;
  }
  for (int i = 0; i < S; i += 256) {
    int sp = i + tid;
    u16 outv[16];
#pragma unroll
    for (int c = 0; c < 16; ++c) {
      float h = xs[c * 1024 + sp] * gm[c] + bt[c];
      outv[c] = f2bf(h);
    }
    u16* dst = HT + ((size_t)n * S + sp) * C + g * cpg;
    *(int4*)dst = *(int4*)&outv[0];
    *(int4*)&dst[8] = *(int4*)&outv[8];
  }
}

// =================== 256x128x32 2-phase GEMM body (8 waves) ================
// Round-8/15 proven structure. epi_mode: 0 normal, 1 expP+atomic lsum,
// 2 colscale 1/epi_ptr[col].
__device__ __forceinline__ void gemm_body(
    int bid, int nblk,
    const u16* __restrict__ A, long lda, long strideA,
    const u16* __restrict__ B, long ldb, long strideB,
    void* __restrict__ Out, long ldo, long strideO, int out_fp32,
    const float* __restrict__ bias, int bias_mode,
    float scale, const float* __restrict__ residual, int K,
    int nbx, int nby, u16* lds, int epi_mode, float* epi_ptr) {
  u16* As0 = lds;
  u16* Bs0 = lds + 8192;
  u16* As1 = lds + 12288;
  u16* Bs1 = lds + 20480;

  int tid = threadIdx.x;
  int wave = tid >> 6, lane = tid & 63;
  int wr = wave >> 1, wc = wave & 1;
  int l15 = lane & 15, l4 = lane >> 4;

  int tilesPB = nbx * nby;
  int nz = nblk / tilesPB;
  int z, rem;
  if ((nz & 7) == 0) {
    int e = bid & 7, j = bid >> 3;
    z = e + 8 * (j / tilesPB);
    rem = j % tilesPB;
  } else {
    int swz = ((nblk & 7) == 0) ? (bid & 7) * (nblk >> 3) + (bid >> 3) : bid;
    z = swz / tilesPB; rem = swz % tilesPB;
  }
  int bx = rem % nbx, by = rem / nbx;

  const u16* Ab = A + (long)z * strideA + (long)by * 256 * lda;
  const u16* Bb = B + (long)z * strideB + (long)bx * 128 * ldb;

  auto STAGE = [&](u16* Ad, u16* Bd, int kt) {
#pragma unroll
    for (int i = 0; i < 2; ++i) {
      int c = i * 512 + tid;
      int l = c >> 3, p = c & 7;
      int q = p ^ (l & 7);
      int row = 2 * l + (q >> 2);
      long koff = (long)kt * 32 + (q & 3) * 8;
      int lbase = (i * 512 + wave * 64) * 8;
      gload_lds16(Ab + (long)row * lda + koff, Ad + lbase);
    }
    {
      int c = tid;
      int l = c >> 3, p = c & 7;
      int q = p ^ (l & 7);
      int row = 2 * l + (q >> 2);
      long koff = (long)kt * 32 + (q & 3) * 8;
      int lbase = (wave * 64) * 8;
      gload_lds16(Bb + (long)row * ldb + koff, Bd + lbase);
    }
  };

  f32x4 acc[4][4] = {};

  auto COMPUTE = [&](const u16* Asrc, const u16* Bsrc) {
    bf16x8 af[4], bfr[4];
#pragma unroll
    for (int m = 0; m < 4; ++m) {
      int R = wr * 64 + m * 16 + l15;
      int line = R >> 1;
      int p = ((R & 1) * 4 + l4) ^ (line & 7);
      af[m] = *(const bf16x8*)&Asrc[line * 64 + p * 8];
    }
#pragma unroll
    for (int n = 0; n < 4; ++n) {
      int R = wc * 64 + n * 16 + l15;
      int line = R >> 1;
      int p = ((R & 1) * 4 + l4) ^ (line & 7);
      bfr[n] = *(const bf16x8*)&Bsrc[line * 64 + p * 8];
    }
#pragma unroll
    for (int m = 0; m < 4; ++m)
#pragma unroll
      for (int n = 0; n < 4; ++n)
        acc[m][n] = __builtin_amdgcn_mfma_f32_16x16x32_bf16(
            af[m], bfr[n], acc[m][n], 0, 0, 0);
  };

  int NT = K >> 5;
  u16 *Ar = As0, *Br = Bs0, *Aw = As1, *Bw = Bs1;

  STAGE(Ar, Br, 0);
  asm volatile("s_waitcnt vmcnt(0)" ::: "memory");
  __builtin_amdgcn_sched_barrier(0);
  __builtin_amdgcn_s_barrier();
  __builtin_amdgcn_sched_barrier(0);

  for (int t = 0; t < NT - 1; ++t) {
    STAGE(Aw, Bw, t + 1);
    COMPUTE(Ar, Br);
    asm volatile("s_waitcnt vmcnt(0)" ::: "memory");
    __builtin_amdgcn_sched_barrier(0);
    __builtin_amdgcn_s_barrier();
    __builtin_amdgcn_sched_barrier(0);
    u16* tp;
    tp = Ar; Ar = Aw; Aw = tp;
    tp = Br; Br = Bw; Bw = tp;
  }
  COMPUTE(Ar, Br);

  long orow0 = (long)by * 256 + wr * 64;
  long ocol0 = (long)bx * 128 + wc * 64;
  long rows_pb = 256L * nby;
  long cols_pb = 128L * nbx;

  float inv4[4];
  if (epi_mode == 2) {
#pragma unroll
    for (int n = 0; n < 4; ++n)
      inv4[n] = 1.f / epi_ptr[z * cols_pb + ocol0 + n * 16 + l15];
  }
  float rowpart[4][4];
  if (epi_mode == 1) {
#pragma unroll
    for (int m = 0; m < 4; ++m)
#pragma unroll
      for (int r = 0; r < 4; ++r) rowpart[m][r] = 0.f;
  }

#pragma unroll
  for (int m = 0; m < 4; ++m) {
#pragma unroll
    for (int n = 0; n < 4; ++n) {
#pragma unroll
      for (int r = 0; r < 4; ++r) {
        long row = orow0 + m * 16 + l4 * 4 + r;
        long col = ocol0 + n * 16 + l15;
        long off = (long)z * strideO + row * ldo + col;
        float v = acc[m][n][r] * scale;
        if (epi_mode == 1) {
          u16 e = f2bf(__expf(v));
          ((u16*)Out)[off] = e;
          rowpart[m][r] += bf2f(e);
        } else {
          if (epi_mode == 2) v *= inv4[n];
          if (bias_mode == 1) v += bias[row];
          else if (bias_mode == 2) v += bias[col];
          if (residual) v += residual[off];
          if (out_fp32) ((float*)Out)[off] = v;
          else ((u16*)Out)[off] = f2bf(v);
        }
      }
    }
  }

  if (epi_mode == 1) {
#pragma unroll
    for (int m = 0; m < 4; ++m)
#pragma unroll
      for (int r = 0; r < 4; ++r) {
        float t = rowpart[m][r];
        t += __shfl_xor(t, 1);
        t += __shfl_xor(t, 2);
        t += __shfl_xor(t, 4);
        t += __shfl_xor(t, 8);
        if (l15 == 0) {
          long row = orow0 + m * 16 + l4 * 4 + r;
          atomicAdd(&epi_ptr[z * rows_pb + row], t);
        }
      }
  }
}

// ============ 256x256x64 single-buffer GEMM body (8 waves) =================
// Round-4-verified STAGE/READ pair (8-granule XOR swizzle, 0 conflicts) +
// round-14-verified serial big-step schedule. 64 KB LDS -> 2 blocks/CU.
// Staged panel bytes per output: (1/256+1/256) vs 256x128's (1/256+1/128).
__device__ __forceinline__ void gemm256sq_body(
    int bid, int nblk,
    const u16* __restrict__ A, long lda, long strideA,
    const u16* __restrict__ B, long ldb, long strideB,
    void* __restrict__ Out, long ldo, long strideO,
    const float* __restrict__ bias, int bias_mode,
    float scale, int K, int nbx, int nby, u16* lds,
    int epi_mode, float* epi_ptr) {
  u16* As = lds;            // [256][64] bf16 = 32 KB
  u16* Bs = lds + 16384;    // [256][64]

  int tid = threadIdx.x;
  int wave = tid >> 6, lane = tid & 63;
  int wr = wave >> 2, wc = wave & 3;   // 2 x 4 wave grid, 128x64 per wave
  int l15 = lane & 15, l4 = lane >> 4;

  int tilesPB = nbx * nby;
  int nz = nblk / tilesPB;
  int z, rem;
  if ((nz & 7) == 0) {
    int e = bid & 7, j = bid >> 3;
    z = e + 8 * (j / tilesPB);
    rem = j % tilesPB;
  } else {
    int swz = ((nblk & 7) == 0) ? (bid & 7) * (nblk >> 3) + (bid >> 3) : bid;
    z = swz / tilesPB; rem = swz % tilesPB;
  }
  int bx = rem % nbx, by = rem / nbx;

  const u16* Ab = A + (long)z * strideA + (long)by * 256 * lda;
  const u16* Bb = B + (long)z * strideB + (long)bx * 256 * ldb;

  // stage 256x64 A and B (2048 granules each; round-4-verified pattern)
  auto STAGE = [&](int kt) {
#pragma unroll
    for (int i = 0; i < 4; ++i) {
      int c = i * 512 + tid;            // 0..2047
      int row = c >> 3, p = c & 7;
      int g = p ^ (row & 7);            // inverse swizzle on global source
      long koff = (long)kt * 64 + g * 8;
      int lbase = (i * 512 + wave * 64) * 8;
      gload_lds16(Ab + (long)row * lda + koff, As + lbase);
      gload_lds16(Bb + (long)row * ldb + koff, Bs + lbase);
    }
  };

  f32x4 acc[8][4] = {};

  auto COMPUTE = [&]() {
#pragma unroll
    for (int kh = 0; kh < 2; ++kh) {
      bf16x8 af[8], bfr[4];
#pragma unroll
      for (int m = 0; m < 8; ++m) {
        int R = wr * 128 + m * 16 + l15;
        int p = (kh * 4 + l4) ^ (R & 7);
        af[m] = *(const bf16x8*)&As[R * 64 + p * 8];
      }
#pragma unroll
      for (int n = 0; n < 4; ++n) {
        int R = wc * 64 + n * 16 + l15;
        int p = (kh * 4 + l4) ^ (R & 7);
        bfr[n] = *(const bf16x8*)&Bs[R * 64 + p * 8];
      }
#pragma unroll
      for (int m = 0; m < 8; ++m)
#pragma unroll
        for (int n = 0; n < 4; ++n)
          acc[m][n] = __builtin_amdgcn_mfma_f32_16x16x32_bf16(
              af[m], bfr[n], acc[m][n], 0, 0, 0);
    }
  };

  int NT = K >> 6;  // 8 for K=512
  for (int t = 0; t < NT; ++t) {
    STAGE(t);
    asm volatile("s_waitcnt vmcnt(0)" ::: "memory");
    __builtin_amdgcn_sched_barrier(0);
    __builtin_amdgcn_s_barrier();
    __builtin_amdgcn_sched_barrier(0);
    COMPUTE();
    __builtin_amdgcn_s_barrier();   // reads done before next overwrite
  }

  long orow0 = (long)by * 256 + wr * 128;
  long ocol0 = (long)bx * 256 + wc * 64;
  long rows_pb = 256L * nby;

  float rowpart[8][4];
  if (epi_mode == 1) {
#pragma unroll
    for (int m = 0; m < 8; ++m)
#pragma unroll
      for (int r = 0; r < 4; ++r) rowpart[m][r] = 0.f;
  }

#pragma unroll
  for (int m = 0; m < 8; ++m) {
#pragma unroll
    for (int n = 0; n < 4; ++n) {
#pragma unroll
      for (int r = 0; r < 4; ++r) {
        long row = orow0 + m * 16 + l4 * 4 + r;
        long col = ocol0 + n * 16 + l15;
        long off = (long)z * strideO + row * ldo + col;
        float v = acc[m][n][r] * scale;
        if (epi_mode == 1) {
          u16 e = f2bf(__expf(v));
          ((u16*)Out)[off] = e;
          rowpart[m][r] += bf2f(e);
        } else {
          if (bias_mode == 1) v += bias[row];
          else if (bias_mode == 2) v += bias[col];
          ((u16*)Out)[off] = f2bf(v);
        }
      }
    }
  }

  if (epi_mode == 1) {
#pragma unroll
    for (int m = 0; m < 8; ++m)
#pragma unroll
      for (int r = 0; r < 4; ++r) {
        float t = rowpart[m][r];
        t += __shfl_xor(t, 1);
        t += __shfl_xor(t, 2);
        t += __shfl_xor(t, 4);
        t += __shfl_xor(t, 8);
        if (l15 == 0) {
          long row = orow0 + m * 16 + l4 * 4 + r;
          atomicAdd(&epi_ptr[z * rows_pb + row], t);
        }
      }
  }
}

__global__ __launch_bounds__(512, 4) void gemm256x128_kernel(
    const u16* __restrict__ A, long lda, long strideA,
    const u16* __restrict__ B, long ldb, long strideB,
    void* __restrict__ Out, long ldo, long strideO, int out_fp32,
    const float* __restrict__ bias, int bias_mode,
    float scale, const float* __restrict__ residual, int K, int nbx, int nby,
    int epi_mode, float* epi_ptr) {
  __shared__ u16 lds[24576];
  gemm_body(blockIdx.x, gridDim.x, A, lda, strideA, B, ldb, strideB,
            Out, ldo, strideO, out_fp32, bias, bias_mode, scale, residual,
            K, nbx, nby, lds, epi_mode, epi_ptr);
}

// expP at 256^2: expP[s][t] = exp(scl*QK^T), atomic row sums into lsum
__global__ __launch_bounds__(512, 2) void expp256_kernel(
    const u16* __restrict__ QKT, u16* __restrict__ P,
    float* __restrict__ lsum, float scl, int C, int S) {
  __shared__ u16 lds[32768];
  long S2C = (long)S * 2 * C, SS = (long)S * S;
  gemm256sq_body(blockIdx.x, gridDim.x, QKT, 2 * C, S2C, QKT + C, 2 * C, S2C,
                 P, S, SS, nullptr, 0, scl, C, S / 256, S / 256, lds, 1, lsum);
}

// merged QK-proj (256^2) + V-proj (256x128): 512 blocks, one dispatch
__global__ __launch_bounds__(512, 2) void projqkv_kernel(
    const u16* __restrict__ HT, const u16* __restrict__ Wqk,
    const u16* __restrict__ Wv, u16* __restrict__ QKT, u16* __restrict__ Vb,
    const float* __restrict__ bqk, const float* __restrict__ bv,
    int nQK, int C, int S) {
  __shared__ u16 lds[32768];
  long SC = (long)S * C, S2C = (long)S * 2 * C;
  if ((int)blockIdx.x < nQK) {
    gemm256sq_body(blockIdx.x, nQK, HT, C, SC, Wqk, C, 0, QKT, 2 * C, S2C,
                   bqk, 2, 1.f, C, 2 * C / 256, S / 256, lds, 0, nullptr);
  } else {
    gemm_body(blockIdx.x - nQK, gridDim.x - nQK, Wv, C, 0, HT, C, SC,
              Vb, S, SC, 0, bv, 1, 1.f, nullptr, C, S / 128, C / 256, lds,
              0, nullptr);
  }
}

extern "C" void kernel_launch(void* const* d_in, const int* in_sizes, int n_in,
                              void* d_out, int out_size, void* d_ws, size_t ws_size,
                              hipStream_t stream) {
  const float* x = (const float*)d_in[0];
  const float* gamma = (const float*)d_in[1];
  const float* beta = (const float*)d_in[2];
  const float* wq = (const float*)d_in[3];
  const float* bq = (const float*)d_in[4];
  const float* wk = (const float*)d_in[5];
  const float* bk = (const float*)d_in[6];
  const float* wv = (const float*)d_in[7];
  const float* bv = (const float*)d_in[8];
  const float* wo = (const float*)d_in[9];
  const float* bo = (const float*)d_in[10];

  const int C = 512, S = 1024;
  const int N = in_sizes[0] / (C * S);  // 16
  const long SC = (long)S * C;
  const long S2C = (long)S * 2 * C;
  const long SS = (long)S * S;
  const int CC = C * C;

  char* ws = (char*)d_ws;
  const size_t MB = 1024 * 1024;
  u16* HT = (u16*)(ws + 0 * MB);      // [N,S,C]   0..16 MB
  u16* QKT = (u16*)(ws + 16 * MB);    // [N,S,2C]  16..48 MB
  u16* Vb = (u16*)(ws + 48 * MB);     // [N,C,S]   48..64 MB
  u16* P = (u16*)(ws + 64 * MB);      // [N,S,S]   64..96 MB
  u16* Wqk = (u16*)(ws + 96 * MB);    // [2C,C]
  u16* Wv = Wqk + 2 * CC;
  u16* Wo = Wv + CC;
  float* bqk = (float*)(Wo + CC);     // [2C]
  float* lsum = bqk + 2 * C;          // [N*S]
  u16* H2T = HT;                      // overlay: HT dead after proj phase

  const int NG = N * GROUPS;          // 512

  prep_kernel<<<dim3(NG + 1024 + 4 + 16), 256, 0, stream>>>(
      x, gamma, beta, HT, wq, wk, wv, wo, bq, bk, Wqk, Wv, Wo, bqk, lsum,
      C, S, CC, NG);

  const float scl = 1.0f / sqrtf((float)C);
  const int nQK = (S / 256) * (2 * C / 256) * N;   // 256 (256^2 tiles)
  const int nV = (C / 256) * (S / 128) * N;        // 256

  // merged QK-proj (256^2) + V-proj (256x128)
  projqkv_kernel<<<dim3(nQK + nV), 512, 0, stream>>>(
      HT, Wqk, Wv, QKT, Vb, bqk, bv, nQK, C, S);
  // expP at 256^2 (+ lsum row sums)
  expp256_kernel<<<dim3((S / 256) * (S / 256) * N), 512, 0, stream>>>(
      QKT, P, lsum, scl, C, S);
  // H2Traw[s][c] = sum_t expP[s][t]*V[c][t]
  gemm256x128_kernel<<<dim3((S / 256) * (C / 128) * N), 512, 0, stream>>>(
      P, S, SS, Vb, S, SC, H2T, C, SC, 0, nullptr, 0, 1.f, nullptr, S,
      C / 128, S / 256, 0, nullptr);
  // out[c][s] = x + bo[c] + (sum_k Wo[c][k]*H2Traw[s][k]) / lsum[s]  (fp32)
  gemm256x128_kernel<<<dim3((C / 256) * (S / 128) * N), 512, 0, stream>>>(
      Wo, C, 0, H2T, C, SC, d_out, S, SC, 1, bo, 1, 1.f, x, C,
      S / 128, C / 256, 2, lsum);
}